// Round 5
// baseline (252.025 us; speedup 1.0000x reference)
//
#include <hip/hip_runtime.h>
#include <cstdint>
#include <cstddef>
#include <math.h>

typedef short bf16x8 __attribute__((ext_vector_type(8)));
typedef float f32x4 __attribute__((ext_vector_type(4)));
typedef unsigned long long u64;

#define NEG_HUGE (-3.0e38f)

__device__ __forceinline__ ushort f2bf(float x) {
    union { float f; uint32_t u; } a; a.f = x;
    uint32_t r = a.u + 0x7FFF + ((a.u >> 16) & 1);   // RNE
    return (ushort)(r >> 16);
}

__device__ __forceinline__ void gload_lds16(const void* g, void* l) {
    __builtin_amdgcn_global_load_lds(
        (const __attribute__((address_space(1))) uint32_t*)g,
        (__attribute__((address_space(3))) uint32_t*)l, 16, 0, 0);
}

// raw barrier: LDS writes visible, but vmem loads stay in flight (no vmcnt drain)
#define WAITB() do { asm volatile("s_waitcnt lgkmcnt(0)" ::: "memory"); \
    __builtin_amdgcn_sched_barrier(0); __builtin_amdgcn_s_barrier(); } while (0)

// ---------------- weight prep ----------------
__global__ void prep_conv_T(const float* __restrict__ w, ushort* __restrict__ WT,
                            int Cin, int Cout, int Nrows, int Kpad) {
    int idx = blockIdx.x * 256 + threadIdx.x;
    if (idx >= Nrows * Kpad) return;
    int n = idx / Kpad, k = idx - n * Kpad;
    float val = 0.f;
    if (k < Cin * 3) {
        int co = n / 3, l = n % 3, ci = k / 3, lx = k % 3;
        int t = lx - l + 1;
        if (t >= 0 && t < 3) val = w[(co * Cin + ci) * 3 + t];
    }
    WT[idx] = f2bf(val);
}

__global__ void prep_lin_T(const float* __restrict__ wl, ushort* __restrict__ WT,
                           int K, int Nreal, int Npad) {
    int idx = blockIdx.x * 256 + threadIdx.x;
    if (idx >= Npad * K) return;
    int n = idx / K, k = idx - n * K;
    WT[idx] = (n < Nreal) ? f2bf(wl[n * K + k]) : (ushort)0;
}

// ---------------- kernel 1: conv1 + mask ----------------
// 512 blocks x 32 samples, 8 waves. Stage fp32 state chunk->bf16 LDS (double-buffer),
// one raw barrier per chunk; depth-2 register prefetch of next chunks survives barriers.
__global__ __launch_bounds__(512, 2)
void conv1_kernel(const float* __restrict__ state, const ushort* __restrict__ W1T,
                  const float* __restrict__ b1, ushort* __restrict__ X1g,
                  uint32_t* __restrict__ maskg)
{
    __shared__ ushort stg[2][32][128];     // 2 x 8 KB, swizzled
    __shared__ uint32_t maskw[32][25];
    const int tid = threadIdx.x;
    const int lane = tid & 63, wid = tid >> 6;
    const int m0 = blockIdx.x * 32;

    for (int i = tid; i < 800; i += 512) ((uint32_t*)maskw)[i] = 0;

    const int sr = tid >> 4, seg = tid & 15;       // 16 threads/row, 8 floats each
    const float* srow = state + (size_t)(m0 + sr) * 2400 + seg * 8;

    f32x4 acc[3][2];
    #pragma unroll
    for (int f = 0; f < 3; ++f)
        #pragma unroll
        for (int mi = 0; mi < 2; ++mi) acc[f][mi] = (f32x4){0.f, 0.f, 0.f, 0.f};

    float4 svA[2], svB[2];
    auto loadc = [&](float4 (&sv)[2], int c) {
        int kb = c * 128 + seg * 8;
        if (kb < 2400) {
            sv[0] = *(const float4*)(srow + c * 128);
            sv[1] = *(const float4*)(srow + c * 128 + 4);
        } else {
            sv[0] = (float4){0.f, 0.f, 0.f, 0.f};
            sv[1] = (float4){0.f, 0.f, 0.f, 0.f};
        }
    };
    auto stage_write = [&](float4 (&sv)[2], int c, int buf) {
        int kbase = c * 128 + seg * 8;
        float fv[8] = {sv[0].x, sv[0].y, sv[0].z, sv[0].w,
                       sv[1].x, sv[1].y, sv[1].z, sv[1].w};
        bf16x8 h;
        #pragma unroll
        for (int j = 0; j < 8; ++j) h[j] = (short)f2bf(fv[j]);
        *(bf16x8*)((char*)&stg[buf][sr][0] + ((seg * 16) ^ ((sr & 7) << 4))) = h;
        #pragma unroll
        for (int j = 0; j < 8; ++j) {
            int k = kbase + j;
            if (k % 3 == 2 && fv[j] != 0.0f) {
                int a = k / 3;
                atomicOr(&maskw[sr][a >> 5], 1u << (a & 31));
            }
        }
    };
    auto layer1 = [&](int buf, const ushort* WT) {
        const int ml = lane & 15, kq = lane >> 4;
        const ushort* wrow = WT + (size_t)(wid * 48 + ml) * 2432 + kq * 8;
        #pragma unroll
        for (int ks = 0; ks < 4; ++ks) {
            bf16x8 af[3];
            #pragma unroll
            for (int f = 0; f < 3; ++f)
                af[f] = *(const bf16x8*)(wrow + (size_t)f * 16 * 2432 + ks * 32);
            bf16x8 bv[2];
            #pragma unroll
            for (int mi = 0; mi < 2; ++mi) {
                int m = mi * 16 + ml;
                bv[mi] = *(const bf16x8*)((const char*)&stg[buf][0][0] + m * 256 +
                                          (((ks * 4 + kq) * 16) ^ ((m & 7) << 4)));
            }
            #pragma unroll
            for (int f = 0; f < 3; ++f)
                #pragma unroll
                for (int mi = 0; mi < 2; ++mi)
                    acc[f][mi] = __builtin_amdgcn_mfma_f32_16x16x32_bf16(af[f], bv[mi], acc[f][mi], 0, 0, 0);
        }
    };

    loadc(svA, 0);
    loadc(svB, 1);
    __syncthreads();    // initial: mask zeros visible

    #pragma unroll 1
    for (int p = 0; p < 9; ++p) {
        int c0 = 2 * p, c1 = 2 * p + 1;
        stage_write(svA, c0, 0);
        WAITB();
        loadc(svA, c0 + 2);
        layer1(0, W1T + c0 * 128);
        stage_write(svB, c1, 1);
        WAITB();
        loadc(svB, c1 + 2);            // c1+2 up to 19 -> loadc zero-fills (never staged)
        layer1(1, W1T + c1 * 128);
    }
    stage_write(svA, 18, 0);
    WAITB();
    layer1(0, W1T + 18 * 128);

    // epilogue -> X1g (plain row-major; reader applies source swizzle)
    {
        const int ml = lane & 15, nq4 = (lane >> 4) * 4;
        #pragma unroll
        for (int f = 0; f < 3; ++f) {
            int n4 = wid * 48 + f * 16 + nq4;
            float bv0 = b1[n4 / 3], bv1 = b1[(n4 + 1) / 3];
            float bv2 = b1[(n4 + 2) / 3], bv3 = b1[(n4 + 3) / 3];
            #pragma unroll
            for (int mi = 0; mi < 2; ++mi) {
                int m = mi * 16 + ml;
                ushort4 o;
                o.x = f2bf(fmaxf(acc[f][mi][0] + bv0, 0.f));
                o.y = f2bf(fmaxf(acc[f][mi][1] + bv1, 0.f));
                o.z = f2bf(fmaxf(acc[f][mi][2] + bv2, 0.f));
                o.w = f2bf(fmaxf(acc[f][mi][3] + bv3, 0.f));
                *(ushort4*)(X1g + (size_t)(m0 + m) * 384 + n4) = o;
            }
        }
    }

    // finalize combined mask: visited | user_any | chan_full  (one thread per sample)
    if (tid < 32) {
        uint32_t* mw = &maskw[tid][0];
        const u64 M40 = (1ull << 40) - 1;
        u64 ua = 0; uint32_t cf = 0;
        #pragma unroll
        for (int g = 0; g < 5; ++g) {
            uint32_t w0 = mw[5*g], w1 = mw[5*g+1], w2 = mw[5*g+2], w3 = mw[5*g+3], w4 = mw[5*g+4];
            u64 c0 = ( (u64)w0        | ((u64)w1 << 32)) & M40;
            u64 c1 = (((u64)w1 >> 8)  | ((u64)w2 << 24)) & M40;
            u64 c2 = (((u64)w2 >> 16) | ((u64)w3 << 16)) & M40;
            u64 c3 = (((u64)w3 >> 24) | ((u64)w4 << 8))  & M40;
            ua |= c0 | c1 | c2 | c3;
            if (__popcll(c0) >= 2) cf |= 1u << (4*g);
            if (__popcll(c1) >= 2) cf |= 1u << (4*g+1);
            if (__popcll(c2) >= 2) cf |= 1u << (4*g+2);
            if (__popcll(c3) >= 2) cf |= 1u << (4*g+3);
        }
        uint32_t* mg = maskg + (size_t)(m0 + tid) * 25;
        #pragma unroll
        for (int g = 0; g < 5; ++g) {
            uint32_t w0 = mw[5*g], w1 = mw[5*g+1], w2 = mw[5*g+2], w3 = mw[5*g+3], w4 = mw[5*g+4];
            u64 c0 = ( (u64)w0        | ((u64)w1 << 32)) & M40;
            u64 c1 = (((u64)w1 >> 8)  | ((u64)w2 << 24)) & M40;
            u64 c2 = (((u64)w2 >> 16) | ((u64)w3 << 16)) & M40;
            u64 c3 = (((u64)w3 >> 24) | ((u64)w4 << 8))  & M40;
            u64 m0v = c0 | ua | (((cf >> (4*g))     & 1u) ? M40 : 0ull);
            u64 m1v = c1 | ua | (((cf >> (4*g + 1)) & 1u) ? M40 : 0ull);
            u64 m2v = c2 | ua | (((cf >> (4*g + 2)) & 1u) ? M40 : 0ull);
            u64 m3v = c3 | ua | (((cf >> (4*g + 3)) & 1u) ? M40 : 0ull);
            mg[5*g]   = (uint32_t)m0v;
            mg[5*g+1] = (uint32_t)(m0v >> 32) | (uint32_t)(m1v << 8);
            mg[5*g+2] = (uint32_t)(m1v >> 24) | (uint32_t)(m2v << 16);
            mg[5*g+3] = (uint32_t)(m2v >> 16) | (uint32_t)(m3v << 24);
            mg[5*g+4] = (uint32_t)(m3v >> 8);
        }
    }
}

// ---------------- kernel 2: layers 2..5 ----------------
// Weight A-fragments with explicit depth-1 register prefetch (static A/B buffers).
template<int NF, int MF, int KPAIRS, int LDX>
__device__ __forceinline__ void layer_pf(const char* xlds, const ushort* __restrict__ WT,
                                         const int ldw, int wn0, int mbase, int lane,
                                         f32x4 (&acc)[NF][MF]) {
    const int ml = lane & 15, kq = lane >> 4;
    const ushort* wrow = WT + (size_t)(wn0 + ml) * ldw + kq * 8;
    bf16x8 afA[NF], afB[NF];
    #pragma unroll
    for (int f = 0; f < NF; ++f) afA[f] = *(const bf16x8*)(wrow + (size_t)f * 16 * ldw);
    #pragma unroll
    for (int p = 0; p < KPAIRS; ++p) {
        const int ks0 = 2 * p, ks1 = 2 * p + 1;
        #pragma unroll
        for (int f = 0; f < NF; ++f)
            afB[f] = *(const bf16x8*)(wrow + (size_t)f * 16 * ldw + ks1 * 32);
        bf16x8 bv[MF];
        #pragma unroll
        for (int mi = 0; mi < MF; ++mi) {
            int m = mbase + mi * 16 + ml;
            bv[mi] = *(const bf16x8*)(xlds + m * LDX + (((ks0 * 4 + kq) * 16) ^ ((m & 7) << 4)));
        }
        #pragma unroll
        for (int f = 0; f < NF; ++f)
            #pragma unroll
            for (int mi = 0; mi < MF; ++mi)
                acc[f][mi] = __builtin_amdgcn_mfma_f32_16x16x32_bf16(afA[f], bv[mi], acc[f][mi], 0, 0, 0);
        const int ksn = (p + 1 < KPAIRS) ? (2 * p + 2) : 0;   // last: dummy reload of k=0
        #pragma unroll
        for (int f = 0; f < NF; ++f)
            afA[f] = *(const bf16x8*)(wrow + (size_t)f * 16 * ldw + ksn * 32);
        #pragma unroll
        for (int mi = 0; mi < MF; ++mi) {
            int m = mbase + mi * 16 + ml;
            bv[mi] = *(const bf16x8*)(xlds + m * LDX + (((ks1 * 4 + kq) * 16) ^ ((m & 7) << 4)));
        }
        #pragma unroll
        for (int f = 0; f < NF; ++f)
            #pragma unroll
            for (int mi = 0; mi < MF; ++mi)
                acc[f][mi] = __builtin_amdgcn_mfma_f32_16x16x32_bf16(afB[f], bv[mi], acc[f][mi], 0, 0, 0);
    }
}

template<int NF, int MF, bool RELU, bool BDIV3>
__device__ __forceinline__ void epi_lds(f32x4 (&acc)[NF][MF], char* xout, int ldo,
                                        const float* __restrict__ bias,
                                        int wn0, int mbase, int lane) {
    const int ml = lane & 15, nq4 = (lane >> 4) * 4;
    #pragma unroll
    for (int f = 0; f < NF; ++f) {
        const int n4 = wn0 + f * 16 + nq4;
        float bv[4];
        #pragma unroll
        for (int r = 0; r < 4; ++r) bv[r] = bias[BDIV3 ? (n4 + r) / 3 : (n4 + r)];
        #pragma unroll
        for (int mi = 0; mi < MF; ++mi) {
            int m = mbase + mi * 16 + ml;
            float x0 = acc[f][mi][0] + bv[0], x1 = acc[f][mi][1] + bv[1];
            float x2 = acc[f][mi][2] + bv[2], x3 = acc[f][mi][3] + bv[3];
            if (RELU) { x0 = fmaxf(x0, 0.f); x1 = fmaxf(x1, 0.f);
                        x2 = fmaxf(x2, 0.f); x3 = fmaxf(x3, 0.f); }
            ushort4 o = {f2bf(x0), f2bf(x1), f2bf(x2), f2bf(x3)};
            *(ushort4*)(xout + m * ldo + ((n4 * 2) ^ ((m & 7) << 4))) = o;
        }
    }
}

__global__ __launch_bounds__(512, 2)
void rest_kernel(const ushort* __restrict__ X1g,
                 const ushort* __restrict__ W2T, const float* __restrict__ b2,
                 const ushort* __restrict__ W3T, const float* __restrict__ b3,
                 const ushort* __restrict__ WL1T, const float* __restrict__ bl1,
                 const ushort* __restrict__ WL2T, const float* __restrict__ bl2,
                 const uint32_t* __restrict__ maskg, float* __restrict__ out)
{
    extern __shared__ char lds[];
    char* X1L = lds;              // 32 x 768 B = 24576   (X1, then X3)
    char* X2L = lds + 24576;      // 32 x 1536 B = 49152  (X2, then X4 ld 384)
    const int tid = threadIdx.x, lane = tid & 63, wid = tid >> 6;
    const int m0 = blockIdx.x * 32;

    // stage X1 tile: linear LDS dest + source-swizzled global octet (rule #21)
    #pragma unroll
    for (int i = 0; i < 3; ++i) {
        int s = i * 512 + tid;                 // 1536 slots of 16 B
        int row = s / 48, o = s - row * 48;
        int go = (o & ~7) | ((o & 7) ^ (row & 7));
        gload_lds16(X1g + (size_t)(m0 + row) * 384 + go * 8, X1L + s * 16);
    }
    __syncthreads();

    // conv2: X1[32][384] -> X2[32][768]
    f32x4 acc2[6][2];
    #pragma unroll
    for (int f = 0; f < 6; ++f)
        #pragma unroll
        for (int mi = 0; mi < 2; ++mi) acc2[f][mi] = (f32x4){0.f, 0.f, 0.f, 0.f};
    layer_pf<6, 2, 6, 768>(X1L, W2T, 384, wid * 96, 0, lane, acc2);
    epi_lds<6, 2, true, true>(acc2, X2L, 1536, b2, wid * 96, 0, lane);
    __syncthreads();

    // conv3: X2 -> X3 (X1L region)
    f32x4 acc3[3][2];
    #pragma unroll
    for (int f = 0; f < 3; ++f)
        #pragma unroll
        for (int mi = 0; mi < 2; ++mi) acc3[f][mi] = (f32x4){0.f, 0.f, 0.f, 0.f};
    layer_pf<3, 2, 12, 1536>(X2L, W3T, 768, wid * 48, 0, lane, acc3);
    epi_lds<3, 2, true, true>(acc3, X1L, 768, b3, wid * 48, 0, lane);
    __syncthreads();

    // lin1: X3[32][384] -> X4[32][192] (X2L region, ld 384)
    const int mh = wid >> 2, nq = wid & 3;
    f32x4 acc4[3][1];
    #pragma unroll
    for (int f = 0; f < 3; ++f) acc4[f][0] = (f32x4){0.f, 0.f, 0.f, 0.f};
    layer_pf<3, 1, 6, 768>(X1L, WL1T, 384, nq * 48, mh * 16, lane, acc4);
    epi_lds<3, 1, true, false>(acc4, X2L, 384, bl1, nq * 48, mh * 16, lane);
    __syncthreads();

    // lin2: X4[32][192] -> out[B][800] f32 + mask
    f32x4 acc5[7][2];
    #pragma unroll
    for (int f = 0; f < 7; ++f)
        #pragma unroll
        for (int mi = 0; mi < 2; ++mi) acc5[f][mi] = (f32x4){0.f, 0.f, 0.f, 0.f};
    layer_pf<7, 2, 3, 384>(X2L, WL2T, 192, wid * 112, 0, lane, acc5);
    {
        const int ml = lane & 15, nq4 = (lane >> 4) * 4;
        #pragma unroll
        for (int f = 0; f < 7; ++f) {
            int nf = wid * 112 + f * 16;
            if (nf < 800) {
                int n4 = nf + nq4, sh = n4 & 31;
                float bv0 = bl2[n4], bv1 = bl2[n4 + 1], bv2 = bl2[n4 + 2], bv3 = bl2[n4 + 3];
                #pragma unroll
                for (int mi = 0; mi < 2; ++mi) {
                    int m = mi * 16 + ml;
                    uint32_t mwv = maskg[(size_t)(m0 + m) * 25 + (nf >> 5)];
                    float4 v;
                    v.x = ((mwv >> (sh + 0)) & 1u) ? NEG_HUGE : (acc5[f][mi][0] + bv0);
                    v.y = ((mwv >> (sh + 1)) & 1u) ? NEG_HUGE : (acc5[f][mi][1] + bv1);
                    v.z = ((mwv >> (sh + 2)) & 1u) ? NEG_HUGE : (acc5[f][mi][2] + bv2);
                    v.w = ((mwv >> (sh + 3)) & 1u) ? NEG_HUGE : (acc5[f][mi][3] + bv3);
                    *(float4*)(out + (size_t)(m0 + m) * 800 + n4) = v;
                }
            }
        }
    }
}

__global__ void ws_fail_kernel(float* out) {
    if (threadIdx.x == 0 && blockIdx.x == 0) out[0] = NAN;
}

extern "C" void kernel_launch(void* const* d_in, const int* in_sizes, int n_in,
                              void* d_out, int out_size, void* d_ws, size_t ws_size,
                              hipStream_t stream) {
    const float* state = (const float*)d_in[0];
    const float* w1  = (const float*)d_in[1];
    const float* b1  = (const float*)d_in[2];
    const float* w2  = (const float*)d_in[3];
    const float* b2  = (const float*)d_in[4];
    const float* w3  = (const float*)d_in[5];
    const float* b3  = (const float*)d_in[6];
    const float* wl1 = (const float*)d_in[7];
    const float* bl1 = (const float*)d_in[8];
    const float* wl2 = (const float*)d_in[9];
    const float* bl2 = (const float*)d_in[10];
    float* out = (float*)d_out;

    char* ws = (char*)d_ws;
    size_t off = 0;
    auto carve = [&](size_t bytes) {
        char* p = ws + off;
        off = (off + bytes + 255) & ~(size_t)255;
        return p;
    };
    ushort* W1T  = (ushort*)carve(384ull * 2432 * 2);
    ushort* W2T  = (ushort*)carve(768ull * 384 * 2);
    ushort* W3T  = (ushort*)carve(384ull * 768 * 2);
    ushort* WL1T = (ushort*)carve(192ull * 384 * 2);
    ushort* WL2T = (ushort*)carve(896ull * 192 * 2);
    ushort* X1g  = (ushort*)carve(16384ull * 384 * 2);
    uint32_t* maskg = (uint32_t*)carve(16384ull * 25 * 4);

    if (off > ws_size) {
        ws_fail_kernel<<<1, 64, 0, stream>>>(out);
        return;
    }

    prep_conv_T<<<(384 * 2432 + 255) / 256, 256, 0, stream>>>(w1, W1T, 800, 128, 384, 2432);
    prep_conv_T<<<(768 * 384 + 255) / 256, 256, 0, stream>>>(w2, W2T, 128, 256, 768, 384);
    prep_conv_T<<<(384 * 768 + 255) / 256, 256, 0, stream>>>(w3, W3T, 256, 128, 384, 768);
    prep_lin_T<<<(192 * 384 + 255) / 256, 256, 0, stream>>>(wl1, WL1T, 384, 192, 192);
    prep_lin_T<<<(896 * 192 + 255) / 256, 256, 0, stream>>>(wl2, WL2T, 192, 800, 896);

    conv1_kernel<<<512, 512, 0, stream>>>(state, W1T, b1, X1g, maskg);

    hipFuncSetAttribute(reinterpret_cast<const void*>(rest_kernel),
                        hipFuncAttributeMaxDynamicSharedMemorySize, 73728);
    rest_kernel<<<512, 512, 73728, stream>>>(X1g, W2T, b2, W3T, b3,
                                             WL1T, bl1, WL2T, bl2, maskg, out);
}

// Round 6
// 187.407 us; speedup vs baseline: 1.3448x; 1.3448x over previous
//
#include <hip/hip_runtime.h>
#include <cstdint>
#include <cstddef>
#include <math.h>

typedef short bf16x8 __attribute__((ext_vector_type(8)));
typedef float f32x4 __attribute__((ext_vector_type(4)));
typedef unsigned long long u64;

#define NEG_HUGE (-3.0e38f)

__device__ __forceinline__ ushort f2bf(float x) {
    union { float f; uint32_t u; } a; a.f = x;
    uint32_t r = a.u + 0x7FFF + ((a.u >> 16) & 1);   // RNE
    return (ushort)(r >> 16);
}

__device__ __forceinline__ void gload_lds16(const void* g, void* l) {
    __builtin_amdgcn_global_load_lds(
        (const __attribute__((address_space(1))) uint32_t*)g,
        (__attribute__((address_space(3))) uint32_t*)l, 16, 0, 0);
}

// ---------------- weight prep ----------------
__global__ void prep_conv_T(const float* __restrict__ w, ushort* __restrict__ WT,
                            int Cin, int Cout, int Nrows, int Kpad) {
    int idx = blockIdx.x * 256 + threadIdx.x;
    if (idx >= Nrows * Kpad) return;
    int n = idx / Kpad, k = idx - n * Kpad;
    float val = 0.f;
    if (k < Cin * 3) {
        int co = n / 3, l = n % 3, ci = k / 3, lx = k % 3;
        int t = lx - l + 1;
        if (t >= 0 && t < 3) val = w[(co * Cin + ci) * 3 + t];
    }
    WT[idx] = f2bf(val);
}

__global__ void prep_lin_T(const float* __restrict__ wl, ushort* __restrict__ WT,
                           int K, int Nreal, int Npad) {
    int idx = blockIdx.x * 256 + threadIdx.x;
    if (idx >= Npad * K) return;
    int n = idx / K, k = idx - n * K;
    WT[idx] = (n < Nreal) ? f2bf(wl[n * K + k]) : (ushort)0;
}

// ---------------- kernel 1: conv1 + mask (counted-vmcnt pipeline) ----------------
// 256 blocks x 64 rows, full N=384. 8 waves (2 mw x 4 nw), wave tile 32 rows x 96 cols.
// BK=64, 38 chunks. LDS: W dbuf 2x48K (global_load_lds from L2), state dbuf 2x8K
// (reg-staged fp32->bf16 + mask bits), mask 6.4K. One raw barrier + one vmcnt(8)/chunk;
// issue order per chunk: [S(c+2)] pre-barrier, [W(c+1)] post-barrier, so the wait for
// W(c) (vmcnt(8), leaves newest 8 = S(c+2)2+W(c+1)6) never waits a fresh HBM load.
__global__ __launch_bounds__(512, 1)
void conv1_kernel(const float* __restrict__ state, const ushort* __restrict__ W1T,
                  const float* __restrict__ b1, ushort* __restrict__ X1g,
                  uint32_t* __restrict__ maskg)
{
    extern __shared__ char lds[];
    char* Wb0 = lds;                       // 48 KB
    char* Wb1 = lds + 49152;               // 48 KB
    char* Sb0 = lds + 98304;               // 8 KB
    char* Sb1 = lds + 106496;              // 8 KB
    uint32_t* maskw = (uint32_t*)(lds + 114688);   // [64][25]

    const int tid = threadIdx.x, lane = tid & 63, wid = tid >> 6;
    const int m0 = blockIdx.x * 64;
    const int mbase = (wid >> 2) * 32;     // wave row offset
    const int wn0 = (wid & 3) * 96;        // wave col offset
    const int ml = lane & 15, kq = lane >> 4;

    const int srow = tid >> 3, seg = tid & 7;      // 8 threads/row, 8 floats each
    const float* sbase = state + (size_t)(m0 + srow) * 2400 + seg * 8;

    f32x4 acc[6][2];
    #pragma unroll
    for (int f = 0; f < 6; ++f)
        #pragma unroll
        for (int mi = 0; mi < 2; ++mi) acc[f][mi] = (f32x4){0.f, 0.f, 0.f, 0.f};

    auto loadW = [&](int c, char* dst) {   // 48KB slice of W1T cols [c*64, c*64+64)
        const ushort* wsrc = W1T + (size_t)c * 64;
        #pragma unroll
        for (int i = 0; i < 6; ++i) {
            int s = i * 512 + tid;                   // 16B slot
            int r = s >> 3, o8 = s & 7;              // row 0..383, k-octet slot
            gload_lds16(wsrc + (size_t)r * 2432 + (size_t)((o8 ^ (r & 7)) * 8),
                        dst + s * 16);               // pre-swizzled source, linear dest
        }
    };
    auto loadS = [&](float4 (&sv)[2], int c) {
        int kb = c * 64 + seg * 8;
        if (kb < 2400) {
            sv[0] = *(const float4*)(sbase + c * 64);
            sv[1] = *(const float4*)(sbase + c * 64 + 4);
        } else {
            sv[0] = (float4){0.f, 0.f, 0.f, 0.f};
            sv[1] = (float4){0.f, 0.f, 0.f, 0.f};
        }
    };
    auto stageS = [&](float4 (&sv)[2], char* dst, int c) {
        float fv[8] = {sv[0].x, sv[0].y, sv[0].z, sv[0].w,
                       sv[1].x, sv[1].y, sv[1].z, sv[1].w};
        bf16x8 h;
        #pragma unroll
        for (int j = 0; j < 8; ++j) h[j] = (short)f2bf(fv[j]);
        *(bf16x8*)(dst + srow * 128 + ((seg * 16) ^ ((srow & 7) << 4))) = h;
        int kbase = c * 64 + seg * 8;
        #pragma unroll
        for (int j = 0; j < 8; ++j) {
            int k = kbase + j;
            if (k % 3 == 2 && fv[j] != 0.0f) {
                int a = k / 3;
                atomicOr(&maskw[srow * 25 + (a >> 5)], 1u << (a & 31));
            }
        }
    };
    auto mfmaC = [&](const char* wb, const char* sb) {
        #pragma unroll
        for (int ks = 0; ks < 2; ++ks) {
            bf16x8 af[6], bv[2];
            #pragma unroll
            for (int f = 0; f < 6; ++f) {
                int n = wn0 + f * 16 + ml;
                af[f] = *(const bf16x8*)(wb + n * 128 + (((ks * 4 + kq) * 16) ^ ((n & 7) << 4)));
            }
            #pragma unroll
            for (int mi = 0; mi < 2; ++mi) {
                int m = mbase + mi * 16 + ml;
                bv[mi] = *(const bf16x8*)(sb + m * 128 + (((ks * 4 + kq) * 16) ^ ((m & 7) << 4)));
            }
            #pragma unroll
            for (int f = 0; f < 6; ++f)
                #pragma unroll
                for (int mi = 0; mi < 2; ++mi)
                    acc[f][mi] = __builtin_amdgcn_mfma_f32_16x16x32_bf16(af[f], bv[mi], acc[f][mi], 0, 0, 0);
        }
    };

    // prologue
    for (int i = tid; i < 64 * 25; i += 512) maskw[i] = 0;
    loadW(0, Wb0);
    float4 svA[2], svB[2];
    loadS(svA, 0);
    loadS(svB, 1);
    asm volatile("s_waitcnt lgkmcnt(0)" ::: "memory");
    __builtin_amdgcn_sched_barrier(0);
    __builtin_amdgcn_s_barrier();
    __builtin_amdgcn_sched_barrier(0);

    #define BODY(SV, C, SB, WBC, WBN) do {                                   \
        stageS(SV, SB, (C));                                                 \
        loadS(SV, ((C) + 2 > 37) ? 37 : (C) + 2);                            \
        asm volatile("s_waitcnt lgkmcnt(0)" ::: "memory");                   \
        __builtin_amdgcn_sched_barrier(0);                                   \
        __builtin_amdgcn_s_barrier();                                        \
        __builtin_amdgcn_sched_barrier(0);                                   \
        loadW((C) + 1, WBN);                                                 \
        __builtin_amdgcn_sched_barrier(0);                                   \
        asm volatile("s_waitcnt vmcnt(8)" ::: "memory");                     \
        mfmaC(WBC, SB);                                                      \
    } while (0)

    #pragma unroll 1
    for (int p = 0; p < 18; ++p) {
        BODY(svA, 2 * p,     Sb0, Wb0, Wb1);
        BODY(svB, 2 * p + 1, Sb1, Wb1, Wb0);
    }
    BODY(svA, 36, Sb0, Wb0, Wb1);
    // peeled chunk 37
    stageS(svB, Sb1, 37);
    asm volatile("s_waitcnt lgkmcnt(0)" ::: "memory");
    __builtin_amdgcn_sched_barrier(0);
    __builtin_amdgcn_s_barrier();
    __builtin_amdgcn_sched_barrier(0);
    asm volatile("s_waitcnt vmcnt(0)" ::: "memory");
    mfmaC(Wb1, Sb1);
    #undef BODY

    // epilogue -> X1g [16384][384] bf16 row-major
    {
        const int nq4 = (lane >> 4) * 4;
        #pragma unroll
        for (int f = 0; f < 6; ++f) {
            int n4 = wn0 + f * 16 + nq4;
            float bv0 = b1[n4 / 3], bv1 = b1[(n4 + 1) / 3];
            float bv2 = b1[(n4 + 2) / 3], bv3 = b1[(n4 + 3) / 3];
            #pragma unroll
            for (int mi = 0; mi < 2; ++mi) {
                int m = mbase + mi * 16 + ml;
                ushort4 o;
                o.x = f2bf(fmaxf(acc[f][mi][0] + bv0, 0.f));
                o.y = f2bf(fmaxf(acc[f][mi][1] + bv1, 0.f));
                o.z = f2bf(fmaxf(acc[f][mi][2] + bv2, 0.f));
                o.w = f2bf(fmaxf(acc[f][mi][3] + bv3, 0.f));
                *(ushort4*)(X1g + (size_t)(m0 + m) * 384 + n4) = o;
            }
        }
    }

    // finalize combined mask: visited | user_any | chan_full  (one thread per sample)
    if (tid < 64) {
        uint32_t* mw = &maskw[tid * 25];
        const u64 M40 = (1ull << 40) - 1;
        u64 ua = 0; uint32_t cf = 0;
        #pragma unroll
        for (int g = 0; g < 5; ++g) {
            uint32_t w0 = mw[5*g], w1 = mw[5*g+1], w2 = mw[5*g+2], w3 = mw[5*g+3], w4 = mw[5*g+4];
            u64 c0 = ( (u64)w0        | ((u64)w1 << 32)) & M40;
            u64 c1 = (((u64)w1 >> 8)  | ((u64)w2 << 24)) & M40;
            u64 c2 = (((u64)w2 >> 16) | ((u64)w3 << 16)) & M40;
            u64 c3 = (((u64)w3 >> 24) | ((u64)w4 << 8))  & M40;
            ua |= c0 | c1 | c2 | c3;
            if (__popcll(c0) >= 2) cf |= 1u << (4*g);
            if (__popcll(c1) >= 2) cf |= 1u << (4*g+1);
            if (__popcll(c2) >= 2) cf |= 1u << (4*g+2);
            if (__popcll(c3) >= 2) cf |= 1u << (4*g+3);
        }
        uint32_t* mg = maskg + (size_t)(m0 + tid) * 25;
        #pragma unroll
        for (int g = 0; g < 5; ++g) {
            uint32_t w0 = mw[5*g], w1 = mw[5*g+1], w2 = mw[5*g+2], w3 = mw[5*g+3], w4 = mw[5*g+4];
            u64 c0 = ( (u64)w0        | ((u64)w1 << 32)) & M40;
            u64 c1 = (((u64)w1 >> 8)  | ((u64)w2 << 24)) & M40;
            u64 c2 = (((u64)w2 >> 16) | ((u64)w3 << 16)) & M40;
            u64 c3 = (((u64)w3 >> 24) | ((u64)w4 << 8))  & M40;
            u64 m0v = c0 | ua | (((cf >> (4*g))     & 1u) ? M40 : 0ull);
            u64 m1v = c1 | ua | (((cf >> (4*g + 1)) & 1u) ? M40 : 0ull);
            u64 m2v = c2 | ua | (((cf >> (4*g + 2)) & 1u) ? M40 : 0ull);
            u64 m3v = c3 | ua | (((cf >> (4*g + 3)) & 1u) ? M40 : 0ull);
            mg[5*g]   = (uint32_t)m0v;
            mg[5*g+1] = (uint32_t)(m0v >> 32) | (uint32_t)(m1v << 8);
            mg[5*g+2] = (uint32_t)(m1v >> 24) | (uint32_t)(m2v << 16);
            mg[5*g+3] = (uint32_t)(m2v >> 16) | (uint32_t)(m3v << 24);
            mg[5*g+4] = (uint32_t)(m3v >> 8);
        }
    }
}

// ---------------- kernel 2: layers 2..5 (unchanged from R5) ----------------
template<int NF, int MF, int KPAIRS, int LDX>
__device__ __forceinline__ void layer_pf(const char* xlds, const ushort* __restrict__ WT,
                                         const int ldw, int wn0, int mbase, int lane,
                                         f32x4 (&acc)[NF][MF]) {
    const int ml = lane & 15, kq = lane >> 4;
    const ushort* wrow = WT + (size_t)(wn0 + ml) * ldw + kq * 8;
    bf16x8 afA[NF], afB[NF];
    #pragma unroll
    for (int f = 0; f < NF; ++f) afA[f] = *(const bf16x8*)(wrow + (size_t)f * 16 * ldw);
    #pragma unroll
    for (int p = 0; p < KPAIRS; ++p) {
        const int ks0 = 2 * p, ks1 = 2 * p + 1;
        #pragma unroll
        for (int f = 0; f < NF; ++f)
            afB[f] = *(const bf16x8*)(wrow + (size_t)f * 16 * ldw + ks1 * 32);
        bf16x8 bv[MF];
        #pragma unroll
        for (int mi = 0; mi < MF; ++mi) {
            int m = mbase + mi * 16 + ml;
            bv[mi] = *(const bf16x8*)(xlds + m * LDX + (((ks0 * 4 + kq) * 16) ^ ((m & 7) << 4)));
        }
        #pragma unroll
        for (int f = 0; f < NF; ++f)
            #pragma unroll
            for (int mi = 0; mi < MF; ++mi)
                acc[f][mi] = __builtin_amdgcn_mfma_f32_16x16x32_bf16(afA[f], bv[mi], acc[f][mi], 0, 0, 0);
        const int ksn = (p + 1 < KPAIRS) ? (2 * p + 2) : 0;
        #pragma unroll
        for (int f = 0; f < NF; ++f)
            afA[f] = *(const bf16x8*)(wrow + (size_t)f * 16 * ldw + ksn * 32);
        #pragma unroll
        for (int mi = 0; mi < MF; ++mi) {
            int m = mbase + mi * 16 + ml;
            bv[mi] = *(const bf16x8*)(xlds + m * LDX + (((ks1 * 4 + kq) * 16) ^ ((m & 7) << 4)));
        }
        #pragma unroll
        for (int f = 0; f < NF; ++f)
            #pragma unroll
            for (int mi = 0; mi < MF; ++mi)
                acc[f][mi] = __builtin_amdgcn_mfma_f32_16x16x32_bf16(afB[f], bv[mi], acc[f][mi], 0, 0, 0);
    }
}

template<int NF, int MF, bool RELU, bool BDIV3>
__device__ __forceinline__ void epi_lds(f32x4 (&acc)[NF][MF], char* xout, int ldo,
                                        const float* __restrict__ bias,
                                        int wn0, int mbase, int lane) {
    const int ml = lane & 15, nq4 = (lane >> 4) * 4;
    #pragma unroll
    for (int f = 0; f < NF; ++f) {
        const int n4 = wn0 + f * 16 + nq4;
        float bv[4];
        #pragma unroll
        for (int r = 0; r < 4; ++r) bv[r] = bias[BDIV3 ? (n4 + r) / 3 : (n4 + r)];
        #pragma unroll
        for (int mi = 0; mi < MF; ++mi) {
            int m = mbase + mi * 16 + ml;
            float x0 = acc[f][mi][0] + bv[0], x1 = acc[f][mi][1] + bv[1];
            float x2 = acc[f][mi][2] + bv[2], x3 = acc[f][mi][3] + bv[3];
            if (RELU) { x0 = fmaxf(x0, 0.f); x1 = fmaxf(x1, 0.f);
                        x2 = fmaxf(x2, 0.f); x3 = fmaxf(x3, 0.f); }
            ushort4 o = {f2bf(x0), f2bf(x1), f2bf(x2), f2bf(x3)};
            *(ushort4*)(xout + m * ldo + ((n4 * 2) ^ ((m & 7) << 4))) = o;
        }
    }
}

__global__ __launch_bounds__(512, 2)
void rest_kernel(const ushort* __restrict__ X1g,
                 const ushort* __restrict__ W2T, const float* __restrict__ b2,
                 const ushort* __restrict__ W3T, const float* __restrict__ b3,
                 const ushort* __restrict__ WL1T, const float* __restrict__ bl1,
                 const ushort* __restrict__ WL2T, const float* __restrict__ bl2,
                 const uint32_t* __restrict__ maskg, float* __restrict__ out)
{
    extern __shared__ char lds[];
    char* X1L = lds;              // 32 x 768 B = 24576   (X1, then X3)
    char* X2L = lds + 24576;      // 32 x 1536 B = 49152  (X2, then X4 ld 384)
    const int tid = threadIdx.x, lane = tid & 63, wid = tid >> 6;
    const int m0 = blockIdx.x * 32;

    #pragma unroll
    for (int i = 0; i < 3; ++i) {
        int s = i * 512 + tid;
        int row = s / 48, o = s - row * 48;
        int go = (o & ~7) | ((o & 7) ^ (row & 7));
        gload_lds16(X1g + (size_t)(m0 + row) * 384 + go * 8, X1L + s * 16);
    }
    __syncthreads();

    f32x4 acc2[6][2];
    #pragma unroll
    for (int f = 0; f < 6; ++f)
        #pragma unroll
        for (int mi = 0; mi < 2; ++mi) acc2[f][mi] = (f32x4){0.f, 0.f, 0.f, 0.f};
    layer_pf<6, 2, 6, 768>(X1L, W2T, 384, wid * 96, 0, lane, acc2);
    epi_lds<6, 2, true, true>(acc2, X2L, 1536, b2, wid * 96, 0, lane);
    __syncthreads();

    f32x4 acc3[3][2];
    #pragma unroll
    for (int f = 0; f < 3; ++f)
        #pragma unroll
        for (int mi = 0; mi < 2; ++mi) acc3[f][mi] = (f32x4){0.f, 0.f, 0.f, 0.f};
    layer_pf<3, 2, 12, 1536>(X2L, W3T, 768, wid * 48, 0, lane, acc3);
    epi_lds<3, 2, true, true>(acc3, X1L, 768, b3, wid * 48, 0, lane);
    __syncthreads();

    const int mh = wid >> 2, nq = wid & 3;
    f32x4 acc4[3][1];
    #pragma unroll
    for (int f = 0; f < 3; ++f) acc4[f][0] = (f32x4){0.f, 0.f, 0.f, 0.f};
    layer_pf<3, 1, 6, 768>(X1L, WL1T, 384, nq * 48, mh * 16, lane, acc4);
    epi_lds<3, 1, true, false>(acc4, X2L, 384, bl1, nq * 48, mh * 16, lane);
    __syncthreads();

    f32x4 acc5[7][2];
    #pragma unroll
    for (int f = 0; f < 7; ++f)
        #pragma unroll
        for (int mi = 0; mi < 2; ++mi) acc5[f][mi] = (f32x4){0.f, 0.f, 0.f, 0.f};
    layer_pf<7, 2, 3, 384>(X2L, WL2T, 192, wid * 112, 0, lane, acc5);
    {
        const int ml = lane & 15, nq4 = (lane >> 4) * 4;
        #pragma unroll
        for (int f = 0; f < 7; ++f) {
            int nf = wid * 112 + f * 16;
            if (nf < 800) {
                int n4 = nf + nq4, sh = n4 & 31;
                float bv0 = bl2[n4], bv1 = bl2[n4 + 1], bv2 = bl2[n4 + 2], bv3 = bl2[n4 + 3];
                #pragma unroll
                for (int mi = 0; mi < 2; ++mi) {
                    int m = mi * 16 + ml;
                    uint32_t mwv = maskg[(size_t)(m0 + m) * 25 + (nf >> 5)];
                    float4 v;
                    v.x = ((mwv >> (sh + 0)) & 1u) ? NEG_HUGE : (acc5[f][mi][0] + bv0);
                    v.y = ((mwv >> (sh + 1)) & 1u) ? NEG_HUGE : (acc5[f][mi][1] + bv1);
                    v.z = ((mwv >> (sh + 2)) & 1u) ? NEG_HUGE : (acc5[f][mi][2] + bv2);
                    v.w = ((mwv >> (sh + 3)) & 1u) ? NEG_HUGE : (acc5[f][mi][3] + bv3);
                    *(float4*)(out + (size_t)(m0 + m) * 800 + n4) = v;
                }
            }
        }
    }
}

__global__ void ws_fail_kernel(float* out) {
    if (threadIdx.x == 0 && blockIdx.x == 0) out[0] = NAN;
}

extern "C" void kernel_launch(void* const* d_in, const int* in_sizes, int n_in,
                              void* d_out, int out_size, void* d_ws, size_t ws_size,
                              hipStream_t stream) {
    const float* state = (const float*)d_in[0];
    const float* w1  = (const float*)d_in[1];
    const float* b1  = (const float*)d_in[2];
    const float* w2  = (const float*)d_in[3];
    const float* b2  = (const float*)d_in[4];
    const float* w3  = (const float*)d_in[5];
    const float* b3  = (const float*)d_in[6];
    const float* wl1 = (const float*)d_in[7];
    const float* bl1 = (const float*)d_in[8];
    const float* wl2 = (const float*)d_in[9];
    const float* bl2 = (const float*)d_in[10];
    float* out = (float*)d_out;

    char* ws = (char*)d_ws;
    size_t off = 0;
    auto carve = [&](size_t bytes) {
        char* p = ws + off;
        off = (off + bytes + 255) & ~(size_t)255;
        return p;
    };
    ushort* W1T  = (ushort*)carve(384ull * 2432 * 2);
    ushort* W2T  = (ushort*)carve(768ull * 384 * 2);
    ushort* W3T  = (ushort*)carve(384ull * 768 * 2);
    ushort* WL1T = (ushort*)carve(192ull * 384 * 2);
    ushort* WL2T = (ushort*)carve(896ull * 192 * 2);
    ushort* X1g  = (ushort*)carve(16384ull * 384 * 2);
    uint32_t* maskg = (uint32_t*)carve(16384ull * 25 * 4);

    if (off > ws_size) {
        ws_fail_kernel<<<1, 64, 0, stream>>>(out);
        return;
    }

    prep_conv_T<<<(384 * 2432 + 255) / 256, 256, 0, stream>>>(w1, W1T, 800, 128, 384, 2432);
    prep_conv_T<<<(768 * 384 + 255) / 256, 256, 0, stream>>>(w2, W2T, 128, 256, 768, 384);
    prep_conv_T<<<(384 * 768 + 255) / 256, 256, 0, stream>>>(w3, W3T, 256, 128, 384, 768);
    prep_lin_T<<<(192 * 384 + 255) / 256, 256, 0, stream>>>(wl1, WL1T, 384, 192, 192);
    prep_lin_T<<<(896 * 192 + 255) / 256, 256, 0, stream>>>(wl2, WL2T, 192, 800, 896);

    hipFuncSetAttribute(reinterpret_cast<const void*>(conv1_kernel),
                        hipFuncAttributeMaxDynamicSharedMemorySize, 121088);
    conv1_kernel<<<256, 512, 121088, stream>>>(state, W1T, b1, X1g, maskg);

    hipFuncSetAttribute(reinterpret_cast<const void*>(rest_kernel),
                        hipFuncAttributeMaxDynamicSharedMemorySize, 73728);
    rest_kernel<<<512, 512, 73728, stream>>>(X1g, W2T, b2, W3T, b3,
                                             WL1T, bl1, WL2T, bl2, maskg, out);
}

// Round 7
// 164.252 us; speedup vs baseline: 1.5344x; 1.1410x over previous
//
#include <hip/hip_runtime.h>
#include <cstdint>
#include <cstddef>
#include <math.h>

typedef short bf16x8 __attribute__((ext_vector_type(8)));
typedef float f32x4 __attribute__((ext_vector_type(4)));
typedef unsigned long long u64;

#define NEG_HUGE (-3.0e38f)

__device__ __forceinline__ ushort f2bf(float x) {
    union { float f; uint32_t u; } a; a.f = x;
    uint32_t r = a.u + 0x7FFF + ((a.u >> 16) & 1);   // RNE
    return (ushort)(r >> 16);
}

__device__ __forceinline__ void gload_lds16(const void* g, void* l) {
    __builtin_amdgcn_global_load_lds(
        (const __attribute__((address_space(1))) uint32_t*)g,
        (__attribute__((address_space(3))) uint32_t*)l, 16, 0, 0);
}

#define VMCNT0_BAR() do { \
    asm volatile("s_waitcnt vmcnt(0)" ::: "memory"); \
    __builtin_amdgcn_sched_barrier(0); \
    __builtin_amdgcn_s_barrier(); \
    __builtin_amdgcn_sched_barrier(0); } while (0)

// ---------------- weight prep ----------------
__global__ void prep_conv_T(const float* __restrict__ w, ushort* __restrict__ WT,
                            int Cin, int Cout, int Nrows, int Kpad) {
    int idx = blockIdx.x * 256 + threadIdx.x;
    if (idx >= Nrows * Kpad) return;
    int n = idx / Kpad, k = idx - n * Kpad;
    float val = 0.f;
    if (k < Cin * 3) {
        int co = n / 3, l = n % 3, ci = k / 3, lx = k % 3;
        int t = lx - l + 1;
        if (t >= 0 && t < 3) val = w[(co * Cin + ci) * 3 + t];
    }
    WT[idx] = f2bf(val);
}

__global__ void prep_lin_T(const float* __restrict__ wl, ushort* __restrict__ WT,
                           int K, int Nreal, int Npad) {
    int idx = blockIdx.x * 256 + threadIdx.x;
    if (idx >= Npad * K) return;
    int n = idx / K, k = idx - n * K;
    WT[idx] = (n < Nreal) ? f2bf(wl[n * K + k]) : (ushort)0;
}

// ---------------- kernel 1: conv1 + mask (unchanged from R6) ----------------
__global__ __launch_bounds__(512, 1)
void conv1_kernel(const float* __restrict__ state, const ushort* __restrict__ W1T,
                  const float* __restrict__ b1, ushort* __restrict__ X1g,
                  uint32_t* __restrict__ maskg)
{
    extern __shared__ char lds[];
    char* Wb0 = lds;
    char* Wb1 = lds + 49152;
    char* Sb0 = lds + 98304;
    char* Sb1 = lds + 106496;
    uint32_t* maskw = (uint32_t*)(lds + 114688);

    const int tid = threadIdx.x, lane = tid & 63, wid = tid >> 6;
    const int m0 = blockIdx.x * 64;
    const int mbase = (wid >> 2) * 32;
    const int wn0 = (wid & 3) * 96;
    const int ml = lane & 15, kq = lane >> 4;

    const int srow = tid >> 3, seg = tid & 7;
    const float* sbase = state + (size_t)(m0 + srow) * 2400 + seg * 8;

    f32x4 acc[6][2];
    #pragma unroll
    for (int f = 0; f < 6; ++f)
        #pragma unroll
        for (int mi = 0; mi < 2; ++mi) acc[f][mi] = (f32x4){0.f, 0.f, 0.f, 0.f};

    auto loadW = [&](int c, char* dst) {
        const ushort* wsrc = W1T + (size_t)c * 64;
        #pragma unroll
        for (int i = 0; i < 6; ++i) {
            int s = i * 512 + tid;
            int r = s >> 3, o8 = s & 7;
            gload_lds16(wsrc + (size_t)r * 2432 + (size_t)((o8 ^ (r & 7)) * 8),
                        dst + s * 16);
        }
    };
    auto loadS = [&](float4 (&sv)[2], int c) {
        int kb = c * 64 + seg * 8;
        if (kb < 2400) {
            sv[0] = *(const float4*)(sbase + c * 64);
            sv[1] = *(const float4*)(sbase + c * 64 + 4);
        } else {
            sv[0] = (float4){0.f, 0.f, 0.f, 0.f};
            sv[1] = (float4){0.f, 0.f, 0.f, 0.f};
        }
    };
    auto stageS = [&](float4 (&sv)[2], char* dst, int c) {
        float fv[8] = {sv[0].x, sv[0].y, sv[0].z, sv[0].w,
                       sv[1].x, sv[1].y, sv[1].z, sv[1].w};
        bf16x8 h;
        #pragma unroll
        for (int j = 0; j < 8; ++j) h[j] = (short)f2bf(fv[j]);
        *(bf16x8*)(dst + srow * 128 + ((seg * 16) ^ ((srow & 7) << 4))) = h;
        int kbase = c * 64 + seg * 8;
        #pragma unroll
        for (int j = 0; j < 8; ++j) {
            int k = kbase + j;
            if (k % 3 == 2 && fv[j] != 0.0f) {
                int a = k / 3;
                atomicOr(&maskw[srow * 25 + (a >> 5)], 1u << (a & 31));
            }
        }
    };
    auto mfmaC = [&](const char* wb, const char* sb) {
        #pragma unroll
        for (int ks = 0; ks < 2; ++ks) {
            bf16x8 af[6], bv[2];
            #pragma unroll
            for (int f = 0; f < 6; ++f) {
                int n = wn0 + f * 16 + ml;
                af[f] = *(const bf16x8*)(wb + n * 128 + (((ks * 4 + kq) * 16) ^ ((n & 7) << 4)));
            }
            #pragma unroll
            for (int mi = 0; mi < 2; ++mi) {
                int m = mbase + mi * 16 + ml;
                bv[mi] = *(const bf16x8*)(sb + m * 128 + (((ks * 4 + kq) * 16) ^ ((m & 7) << 4)));
            }
            #pragma unroll
            for (int f = 0; f < 6; ++f)
                #pragma unroll
                for (int mi = 0; mi < 2; ++mi)
                    acc[f][mi] = __builtin_amdgcn_mfma_f32_16x16x32_bf16(af[f], bv[mi], acc[f][mi], 0, 0, 0);
        }
    };

    for (int i = tid; i < 64 * 25; i += 512) maskw[i] = 0;
    loadW(0, Wb0);
    float4 svA[2], svB[2];
    loadS(svA, 0);
    loadS(svB, 1);
    asm volatile("s_waitcnt lgkmcnt(0)" ::: "memory");
    __builtin_amdgcn_sched_barrier(0);
    __builtin_amdgcn_s_barrier();
    __builtin_amdgcn_sched_barrier(0);

    #define BODY(SV, C, SB, WBC, WBN) do {                                   \
        stageS(SV, SB, (C));                                                 \
        loadS(SV, ((C) + 2 > 37) ? 37 : (C) + 2);                            \
        asm volatile("s_waitcnt lgkmcnt(0)" ::: "memory");                   \
        __builtin_amdgcn_sched_barrier(0);                                   \
        __builtin_amdgcn_s_barrier();                                        \
        __builtin_amdgcn_sched_barrier(0);                                   \
        loadW((C) + 1, WBN);                                                 \
        __builtin_amdgcn_sched_barrier(0);                                   \
        asm volatile("s_waitcnt vmcnt(8)" ::: "memory");                     \
        mfmaC(WBC, SB);                                                      \
    } while (0)

    #pragma unroll 1
    for (int p = 0; p < 18; ++p) {
        BODY(svA, 2 * p,     Sb0, Wb0, Wb1);
        BODY(svB, 2 * p + 1, Sb1, Wb1, Wb0);
    }
    BODY(svA, 36, Sb0, Wb0, Wb1);
    stageS(svB, Sb1, 37);
    asm volatile("s_waitcnt lgkmcnt(0)" ::: "memory");
    __builtin_amdgcn_sched_barrier(0);
    __builtin_amdgcn_s_barrier();
    __builtin_amdgcn_sched_barrier(0);
    asm volatile("s_waitcnt vmcnt(0)" ::: "memory");
    mfmaC(Wb1, Sb1);
    #undef BODY

    {
        const int nq4 = (lane >> 4) * 4;
        #pragma unroll
        for (int f = 0; f < 6; ++f) {
            int n4 = wn0 + f * 16 + nq4;
            float bv0 = b1[n4 / 3], bv1 = b1[(n4 + 1) / 3];
            float bv2 = b1[(n4 + 2) / 3], bv3 = b1[(n4 + 3) / 3];
            #pragma unroll
            for (int mi = 0; mi < 2; ++mi) {
                int m = mbase + mi * 16 + ml;
                ushort4 o;
                o.x = f2bf(fmaxf(acc[f][mi][0] + bv0, 0.f));
                o.y = f2bf(fmaxf(acc[f][mi][1] + bv1, 0.f));
                o.z = f2bf(fmaxf(acc[f][mi][2] + bv2, 0.f));
                o.w = f2bf(fmaxf(acc[f][mi][3] + bv3, 0.f));
                *(ushort4*)(X1g + (size_t)(m0 + m) * 384 + n4) = o;
            }
        }
    }

    if (tid < 64) {
        uint32_t* mw = &maskw[tid * 25];
        const u64 M40 = (1ull << 40) - 1;
        u64 ua = 0; uint32_t cf = 0;
        #pragma unroll
        for (int g = 0; g < 5; ++g) {
            uint32_t w0 = mw[5*g], w1 = mw[5*g+1], w2 = mw[5*g+2], w3 = mw[5*g+3], w4 = mw[5*g+4];
            u64 c0 = ( (u64)w0        | ((u64)w1 << 32)) & M40;
            u64 c1 = (((u64)w1 >> 8)  | ((u64)w2 << 24)) & M40;
            u64 c2 = (((u64)w2 >> 16) | ((u64)w3 << 16)) & M40;
            u64 c3 = (((u64)w3 >> 24) | ((u64)w4 << 8))  & M40;
            ua |= c0 | c1 | c2 | c3;
            if (__popcll(c0) >= 2) cf |= 1u << (4*g);
            if (__popcll(c1) >= 2) cf |= 1u << (4*g+1);
            if (__popcll(c2) >= 2) cf |= 1u << (4*g+2);
            if (__popcll(c3) >= 2) cf |= 1u << (4*g+3);
        }
        uint32_t* mg = maskg + (size_t)(m0 + tid) * 25;
        #pragma unroll
        for (int g = 0; g < 5; ++g) {
            uint32_t w0 = mw[5*g], w1 = mw[5*g+1], w2 = mw[5*g+2], w3 = mw[5*g+3], w4 = mw[5*g+4];
            u64 c0 = ( (u64)w0        | ((u64)w1 << 32)) & M40;
            u64 c1 = (((u64)w1 >> 8)  | ((u64)w2 << 24)) & M40;
            u64 c2 = (((u64)w2 >> 16) | ((u64)w3 << 16)) & M40;
            u64 c3 = (((u64)w3 >> 24) | ((u64)w4 << 8))  & M40;
            u64 m0v = c0 | ua | (((cf >> (4*g))     & 1u) ? M40 : 0ull);
            u64 m1v = c1 | ua | (((cf >> (4*g + 1)) & 1u) ? M40 : 0ull);
            u64 m2v = c2 | ua | (((cf >> (4*g + 2)) & 1u) ? M40 : 0ull);
            u64 m3v = c3 | ua | (((cf >> (4*g + 3)) & 1u) ? M40 : 0ull);
            mg[5*g]   = (uint32_t)m0v;
            mg[5*g+1] = (uint32_t)(m0v >> 32) | (uint32_t)(m1v << 8);
            mg[5*g+2] = (uint32_t)(m1v >> 24) | (uint32_t)(m2v << 16);
            mg[5*g+3] = (uint32_t)(m2v >> 16) | (uint32_t)(m3v << 24);
            mg[5*g+4] = (uint32_t)(m3v >> 8);
        }
    }
}

// ---------------- per-layer pipelined GEMM (layers 2..4) ----------------
// A (activations [B][K] bf16) fully staged in LDS at start; W in K-chunks of 64,
// double-buffered, one vmcnt(0)+barrier per chunk (wait covers only chunk-old loads).
template<int MT, int NT, int K, int MF, int NF, int NWM, bool BDIV3>
__global__ __launch_bounds__(512)
void glayer(const ushort* __restrict__ Xg, const ushort* __restrict__ WT,
            const float* __restrict__ bias, ushort* __restrict__ Yg, int Nout)
{
    constexpr int NC   = K / 64;
    constexpr int AOCT = K / 8;
    constexpr int APT  = MT * AOCT / 512;
    constexpr int WPT  = NT * 8 / 512;
    extern __shared__ char lds[];
    char* Albuf = lds;                            // MT x (2K) bytes
    char* Wbuf0 = lds + MT * K * 2;               // NT x 128 B each
    char* Wbuf1 = Wbuf0 + NT * 128;

    const int tid = threadIdx.x, lane = tid & 63, wid = tid >> 6;
    const int m0 = blockIdx.x * MT;
    const int n0 = blockIdx.y * NT;
    const int ml = lane & 15, kq = lane >> 4;
    const int mbase = (NWM == 1) ? 0 : (wid >> 2) * (MT / 2);
    const int wn0 = ((NWM == 1) ? wid : (wid & 3)) * (NF * 16);

    f32x4 acc[NF][MF];
    #pragma unroll
    for (int f = 0; f < NF; ++f)
        #pragma unroll
        for (int mi = 0; mi < MF; ++mi) acc[f][mi] = (f32x4){0.f, 0.f, 0.f, 0.f};

    auto loadW = [&](int c, char* dst) {
        #pragma unroll
        for (int i = 0; i < WPT; ++i) {
            int s = i * 512 + tid;
            int r = s >> 3, o = s & 7;
            gload_lds16(WT + (size_t)(n0 + r) * K + c * 64 + ((o ^ (r & 7)) * 8),
                        dst + s * 16);
        }
    };
    auto mfmaC = [&](const char* wb, int c) {
        #pragma unroll
        for (int ks = 0; ks < 2; ++ks) {
            bf16x8 af[NF], bv[MF];
            #pragma unroll
            for (int f = 0; f < NF; ++f) {
                int n = wn0 + f * 16 + ml;
                af[f] = *(const bf16x8*)(wb + n * 128 + (((ks * 4 + kq) * 16) ^ ((n & 7) << 4)));
            }
            #pragma unroll
            for (int mi = 0; mi < MF; ++mi) {
                int m = mbase + mi * 16 + ml;
                bv[mi] = *(const bf16x8*)(Albuf + m * (2 * K) +
                            ((((c * 2 + ks) * 4 + kq) * 16) ^ ((m & 7) << 4)));
            }
            #pragma unroll
            for (int f = 0; f < NF; ++f)
                #pragma unroll
                for (int mi = 0; mi < MF; ++mi)
                    acc[f][mi] = __builtin_amdgcn_mfma_f32_16x16x32_bf16(af[f], bv[mi], acc[f][mi], 0, 0, 0);
        }
    };

    // prologue: stage A fully + W(0)
    #pragma unroll
    for (int i = 0; i < APT; ++i) {
        int s = i * 512 + tid;
        int r = s / AOCT, o = s - r * AOCT;
        int go = (o & ~7) | ((o & 7) ^ (r & 7));
        gload_lds16(Xg + (size_t)(m0 + r) * K + go * 8, Albuf + s * 16);
    }
    loadW(0, Wbuf0);
    VMCNT0_BAR();

    #pragma unroll 1
    for (int c = 0; c < NC; ++c) {
        if (c + 1 < NC) loadW(c + 1, (c & 1) ? Wbuf0 : Wbuf1);
        mfmaC((c & 1) ? Wbuf1 : Wbuf0, c);
        if (c + 1 < NC) VMCNT0_BAR();
    }

    // epilogue: bias + relu, bf16 -> Yg row-major
    const int nq4 = (lane >> 4) * 4;
    #pragma unroll
    for (int f = 0; f < NF; ++f) {
        int n4 = n0 + wn0 + f * 16 + nq4;
        float bv0 = bias[BDIV3 ? n4 / 3 : n4];
        float bv1 = bias[BDIV3 ? (n4 + 1) / 3 : n4 + 1];
        float bv2 = bias[BDIV3 ? (n4 + 2) / 3 : n4 + 2];
        float bv3 = bias[BDIV3 ? (n4 + 3) / 3 : n4 + 3];
        #pragma unroll
        for (int mi = 0; mi < MF; ++mi) {
            int m = mbase + mi * 16 + ml;
            ushort4 o;
            o.x = f2bf(fmaxf(acc[f][mi][0] + bv0, 0.f));
            o.y = f2bf(fmaxf(acc[f][mi][1] + bv1, 0.f));
            o.z = f2bf(fmaxf(acc[f][mi][2] + bv2, 0.f));
            o.w = f2bf(fmaxf(acc[f][mi][3] + bv3, 0.f));
            *(ushort4*)(Yg + (size_t)(m0 + m) * Nout + n4) = o;
        }
    }
}

// ---------------- lin2: [B,192] @ WL2T[896,192] -> out[B,800] f32 + mask ----------------
__global__ __launch_bounds__(512)
void lin2_kernel(const ushort* __restrict__ Xg, const ushort* __restrict__ WT,
                 const float* __restrict__ bias, const uint32_t* __restrict__ maskg,
                 float* __restrict__ out)
{
    constexpr int MT = 64, NT = 448, K = 192, NC = 3, MF = 2, NF = 7;
    constexpr int AOCT = K / 8;                   // 24
    extern __shared__ char lds[];
    char* Albuf = lds;                            // 64 x 384 B = 24576
    char* Wbuf0 = lds + MT * K * 2;
    char* Wbuf1 = Wbuf0 + NT * 128;

    const int tid = threadIdx.x, lane = tid & 63, wid = tid >> 6;
    const int m0 = blockIdx.x * MT;
    const int n0 = blockIdx.y * NT;
    const int ml = lane & 15, kq = lane >> 4;
    const int mbase = (wid >> 2) * 32;
    const int wn0 = (wid & 3) * 112;

    f32x4 acc[NF][MF];
    #pragma unroll
    for (int f = 0; f < NF; ++f)
        #pragma unroll
        for (int mi = 0; mi < MF; ++mi) acc[f][mi] = (f32x4){0.f, 0.f, 0.f, 0.f};

    auto loadW = [&](int c, char* dst) {
        #pragma unroll
        for (int i = 0; i < 7; ++i) {
            int s = i * 512 + tid;
            int r = s >> 3, o = s & 7;
            gload_lds16(WT + (size_t)(n0 + r) * K + c * 64 + ((o ^ (r & 7)) * 8),
                        dst + s * 16);
        }
    };
    auto mfmaC = [&](const char* wb, int c) {
        #pragma unroll
        for (int ks = 0; ks < 2; ++ks) {
            bf16x8 af[NF], bv[MF];
            #pragma unroll
            for (int f = 0; f < NF; ++f) {
                int n = wn0 + f * 16 + ml;
                af[f] = *(const bf16x8*)(wb + n * 128 + (((ks * 4 + kq) * 16) ^ ((n & 7) << 4)));
            }
            #pragma unroll
            for (int mi = 0; mi < MF; ++mi) {
                int m = mbase + mi * 16 + ml;
                bv[mi] = *(const bf16x8*)(Albuf + m * (2 * K) +
                            ((((c * 2 + ks) * 4 + kq) * 16) ^ ((m & 7) << 4)));
            }
            #pragma unroll
            for (int f = 0; f < NF; ++f)
                #pragma unroll
                for (int mi = 0; mi < MF; ++mi)
                    acc[f][mi] = __builtin_amdgcn_mfma_f32_16x16x32_bf16(af[f], bv[mi], acc[f][mi], 0, 0, 0);
        }
    };

    #pragma unroll
    for (int i = 0; i < 3; ++i) {
        int s = i * 512 + tid;
        int r = s / AOCT, o = s - r * AOCT;
        int go = (o & ~7) | ((o & 7) ^ (r & 7));
        gload_lds16(Xg + (size_t)(m0 + r) * K + go * 8, Albuf + s * 16);
    }
    loadW(0, Wbuf0);
    VMCNT0_BAR();

    #pragma unroll 1
    for (int c = 0; c < NC; ++c) {
        if (c + 1 < NC) loadW(c + 1, (c & 1) ? Wbuf0 : Wbuf1);
        mfmaC((c & 1) ? Wbuf1 : Wbuf0, c);
        if (c + 1 < NC) VMCNT0_BAR();
    }

    const int nq4 = (lane >> 4) * 4;
    #pragma unroll
    for (int f = 0; f < NF; ++f) {
        int nf = n0 + wn0 + f * 16;
        if (nf < 800) {
            int n4 = nf + nq4, sh = n4 & 31;
            float bv0 = bias[n4], bv1 = bias[n4 + 1], bv2 = bias[n4 + 2], bv3 = bias[n4 + 3];
            #pragma unroll
            for (int mi = 0; mi < MF; ++mi) {
                int m = mbase + mi * 16 + ml;
                uint32_t mwv = maskg[(size_t)(m0 + m) * 25 + (nf >> 5)];
                float4 v;
                v.x = ((mwv >> (sh + 0)) & 1u) ? NEG_HUGE : (acc[f][mi][0] + bv0);
                v.y = ((mwv >> (sh + 1)) & 1u) ? NEG_HUGE : (acc[f][mi][1] + bv1);
                v.z = ((mwv >> (sh + 2)) & 1u) ? NEG_HUGE : (acc[f][mi][2] + bv2);
                v.w = ((mwv >> (sh + 3)) & 1u) ? NEG_HUGE : (acc[f][mi][3] + bv3);
                *(float4*)(out + (size_t)(m0 + m) * 800 + n4) = v;
            }
        }
    }
}

__global__ void ws_fail_kernel(float* out) {
    if (threadIdx.x == 0 && blockIdx.x == 0) out[0] = NAN;
}

extern "C" void kernel_launch(void* const* d_in, const int* in_sizes, int n_in,
                              void* d_out, int out_size, void* d_ws, size_t ws_size,
                              hipStream_t stream) {
    const float* state = (const float*)d_in[0];
    const float* w1  = (const float*)d_in[1];
    const float* b1  = (const float*)d_in[2];
    const float* w2  = (const float*)d_in[3];
    const float* b2  = (const float*)d_in[4];
    const float* w3  = (const float*)d_in[5];
    const float* b3  = (const float*)d_in[6];
    const float* wl1 = (const float*)d_in[7];
    const float* bl1 = (const float*)d_in[8];
    const float* wl2 = (const float*)d_in[9];
    const float* bl2 = (const float*)d_in[10];
    float* out = (float*)d_out;

    char* ws = (char*)d_ws;
    size_t off = 0;
    auto carve = [&](size_t bytes) {
        char* p = ws + off;
        off = (off + bytes + 255) & ~(size_t)255;
        return p;
    };
    ushort* W1T  = (ushort*)carve(384ull * 2432 * 2);
    ushort* W2T  = (ushort*)carve(768ull * 384 * 2);
    ushort* W3T  = (ushort*)carve(384ull * 768 * 2);
    ushort* WL1T = (ushort*)carve(192ull * 384 * 2);
    ushort* WL2T = (ushort*)carve(896ull * 192 * 2);
    ushort* X1g  = (ushort*)carve(16384ull * 384 * 2);
    ushort* X2g  = (ushort*)carve(16384ull * 768 * 2);
    ushort* X3g  = (ushort*)carve(16384ull * 384 * 2);
    ushort* X4g  = (ushort*)carve(16384ull * 192 * 2);
    uint32_t* maskg = (uint32_t*)carve(16384ull * 25 * 4);

    if (off > ws_size) {
        ws_fail_kernel<<<1, 64, 0, stream>>>(out);
        return;
    }

    prep_conv_T<<<(384 * 2432 + 255) / 256, 256, 0, stream>>>(w1, W1T, 800, 128, 384, 2432);
    prep_conv_T<<<(768 * 384 + 255) / 256, 256, 0, stream>>>(w2, W2T, 128, 256, 768, 384);
    prep_conv_T<<<(384 * 768 + 255) / 256, 256, 0, stream>>>(w3, W3T, 256, 128, 384, 768);
    prep_lin_T<<<(192 * 384 + 255) / 256, 256, 0, stream>>>(wl1, WL1T, 384, 192, 192);
    prep_lin_T<<<(896 * 192 + 255) / 256, 256, 0, stream>>>(wl2, WL2T, 192, 800, 896);

    hipFuncSetAttribute(reinterpret_cast<const void*>(conv1_kernel),
                        hipFuncAttributeMaxDynamicSharedMemorySize, 121088);
    conv1_kernel<<<256, 512, 121088, stream>>>(state, W1T, b1, X1g, maskg);

    // conv2: X1[16384,384] @ W2T[768,384] -> X2 ; tiles 64x384, grid 256x2
    auto k2 = glayer<64, 384, 384, 4, 3, 1, true>;
    hipFuncSetAttribute(reinterpret_cast<const void*>(k2),
                        hipFuncAttributeMaxDynamicSharedMemorySize, 147456);
    k2<<<dim3(256, 2), 512, 147456, stream>>>(X1g, W2T, b2, X2g, 768);

    // conv3: X2[16384,768] @ W3T[384,768] -> X3 ; tiles 32x384, grid 512x1
    auto k3 = glayer<32, 384, 768, 2, 3, 1, true>;
    hipFuncSetAttribute(reinterpret_cast<const void*>(k3),
                        hipFuncAttributeMaxDynamicSharedMemorySize, 147456);
    k3<<<dim3(512, 1), 512, 147456, stream>>>(X2g, W3T, b3, X3g, 384);

    // lin1: X3[16384,384] @ WL1T[192,384] -> X4 ; tiles 32x192, grid 512x1
    auto k4 = glayer<32, 192, 384, 1, 3, 2, false>;
    hipFuncSetAttribute(reinterpret_cast<const void*>(k4),
                        hipFuncAttributeMaxDynamicSharedMemorySize, 73728);
    k4<<<dim3(512, 1), 512, 73728, stream>>>(X3g, WL1T, bl1, X4g, 192);

    // lin2 + mask: tiles 64x448, grid 256x2
    hipFuncSetAttribute(reinterpret_cast<const void*>(lin2_kernel),
                        hipFuncAttributeMaxDynamicSharedMemorySize, 139264);
    lin2_kernel<<<dim3(256, 2), 512, 139264, stream>>>(X4g, WL2T, bl2, maskg, out);
}

// Round 8
// 161.982 us; speedup vs baseline: 1.5559x; 1.0140x over previous
//
#include <hip/hip_runtime.h>
#include <cstdint>
#include <cstddef>
#include <math.h>

typedef short bf16x8 __attribute__((ext_vector_type(8)));
typedef float f32x4 __attribute__((ext_vector_type(4)));
typedef unsigned long long u64;

#define NEG_HUGE (-3.0e38f)

__device__ __forceinline__ ushort f2bf(float x) {
    union { float f; uint32_t u; } a; a.f = x;
    uint32_t r = a.u + 0x7FFF + ((a.u >> 16) & 1);   // RNE
    return (ushort)(r >> 16);
}

__device__ __forceinline__ void gload_lds16(const void* g, void* l) {
    __builtin_amdgcn_global_load_lds(
        (const __attribute__((address_space(1))) uint32_t*)g,
        (__attribute__((address_space(3))) uint32_t*)l, 16, 0, 0);
}

#define VMCNT0_BAR() do { \
    asm volatile("s_waitcnt vmcnt(0)" ::: "memory"); \
    __builtin_amdgcn_sched_barrier(0); \
    __builtin_amdgcn_s_barrier(); \
    __builtin_amdgcn_sched_barrier(0); } while (0)

// ---------------- weight prep ----------------
__global__ void prep_conv_T(const float* __restrict__ w, ushort* __restrict__ WT,
                            int Cin, int Cout, int Nrows, int Kpad) {
    int idx = blockIdx.x * 256 + threadIdx.x;
    if (idx >= Nrows * Kpad) return;
    int n = idx / Kpad, k = idx - n * Kpad;
    float val = 0.f;
    if (k < Cin * 3) {
        int co = n / 3, l = n % 3, ci = k / 3, lx = k % 3;
        int t = lx - l + 1;
        if (t >= 0 && t < 3) val = w[(co * Cin + ci) * 3 + t];
    }
    WT[idx] = f2bf(val);
}

__global__ void prep_lin_T(const float* __restrict__ wl, ushort* __restrict__ WT,
                           int K, int Nreal, int Npad) {
    int idx = blockIdx.x * 256 + threadIdx.x;
    if (idx >= Npad * K) return;
    int n = idx / K, k = idx - n * K;
    WT[idx] = (n < Nreal) ? f2bf(wl[n * K + k]) : (ushort)0;
}

// ---------------- kernel 1: conv1 + mask, N-split for 2 blocks/CU ----------------
// grid (256 Mtiles, 2 Nhalves). Block: 64 rows x 192 cols, BK=64, 38 chunks.
// LDS 72KB -> 2 blocks/CU; counted vmcnt(5) leaves S(c+2)[2]+W(c+1)[3] in flight.
__global__ __launch_bounds__(512, 4)
void conv1_kernel(const float* __restrict__ state, const ushort* __restrict__ W1T,
                  const float* __restrict__ b1, ushort* __restrict__ X1g,
                  uint32_t* __restrict__ maskg)
{
    extern __shared__ char lds[];
    char* Wb0 = lds;                               // 192*128 = 24576
    char* Wb1 = lds + 24576;
    char* Sb0 = lds + 49152;                       // 64*128 = 8192
    char* Sb1 = lds + 57344;
    uint32_t* maskw = (uint32_t*)(lds + 65536);    // [64][25] = 6400

    const int tid = threadIdx.x, lane = tid & 63, wid = tid >> 6;
    const int m0 = blockIdx.x * 64;
    const int n0 = blockIdx.y * 192;               // N-half of W1T rows
    const int mbase = (wid >> 2) * 32;
    const int wn0 = (wid & 3) * 48;                // 4 waves x 48 cols = 192
    const int ml = lane & 15, kq = lane >> 4;

    const int srow = tid >> 3, seg = tid & 7;      // 8 threads/row, 8 floats each
    const float* sbase = state + (size_t)(m0 + srow) * 2400 + seg * 8;

    f32x4 acc[3][2];
    #pragma unroll
    for (int f = 0; f < 3; ++f)
        #pragma unroll
        for (int mi = 0; mi < 2; ++mi) acc[f][mi] = (f32x4){0.f, 0.f, 0.f, 0.f};

    auto loadW = [&](int c, char* dst) {           // 24KB: rows n0..n0+191, k-chunk c
        #pragma unroll
        for (int i = 0; i < 3; ++i) {
            int s = i * 512 + tid;
            int r = s >> 3, o8 = s & 7;
            gload_lds16(W1T + (size_t)(n0 + r) * 2432 + c * 64 + ((o8 ^ (r & 7)) * 8),
                        dst + s * 16);
        }
    };
    auto loadS = [&](float4 (&sv)[2], int c) {
        int kb = c * 64 + seg * 8;
        if (kb < 2400) {
            sv[0] = *(const float4*)(sbase + c * 64);
            sv[1] = *(const float4*)(sbase + c * 64 + 4);
        } else {
            sv[0] = (float4){0.f, 0.f, 0.f, 0.f};
            sv[1] = (float4){0.f, 0.f, 0.f, 0.f};
        }
    };
    auto stageS = [&](float4 (&sv)[2], char* dst, int c) {
        float fv[8] = {sv[0].x, sv[0].y, sv[0].z, sv[0].w,
                       sv[1].x, sv[1].y, sv[1].z, sv[1].w};
        bf16x8 h;
        #pragma unroll
        for (int j = 0; j < 8; ++j) h[j] = (short)f2bf(fv[j]);
        *(bf16x8*)(dst + srow * 128 + ((seg * 16) ^ ((srow & 7) << 4))) = h;
        // visited-status bits: k%3==2 positions; kbase%3 in {0,1,2} -> fixed j set
        int kbase = c * 64 + seg * 8;
        int kmod = kbase % 3;
        uint32_t* mrow = &maskw[srow * 25];
        #define MCHK(J) { if (fv[J] != 0.0f) { int a = (kbase + (J)) / 3; \
                          atomicOr(&mrow[a >> 5], 1u << (a & 31)); } }
        if (kmod == 0)      { MCHK(2) MCHK(5) }
        else if (kmod == 1) { MCHK(1) MCHK(4) MCHK(7) }
        else                { MCHK(0) MCHK(3) MCHK(6) }
        #undef MCHK
    };
    auto mfmaC = [&](const char* wb, const char* sb) {
        #pragma unroll
        for (int ks = 0; ks < 2; ++ks) {
            bf16x8 af[3], bv[2];
            #pragma unroll
            for (int f = 0; f < 3; ++f) {
                int n = wn0 + f * 16 + ml;
                af[f] = *(const bf16x8*)(wb + n * 128 + (((ks * 4 + kq) * 16) ^ ((n & 7) << 4)));
            }
            #pragma unroll
            for (int mi = 0; mi < 2; ++mi) {
                int m = mbase + mi * 16 + ml;
                bv[mi] = *(const bf16x8*)(sb + m * 128 + (((ks * 4 + kq) * 16) ^ ((m & 7) << 4)));
            }
            #pragma unroll
            for (int f = 0; f < 3; ++f)
                #pragma unroll
                for (int mi = 0; mi < 2; ++mi)
                    acc[f][mi] = __builtin_amdgcn_mfma_f32_16x16x32_bf16(af[f], bv[mi], acc[f][mi], 0, 0, 0);
        }
    };

    for (int i = tid; i < 64 * 25; i += 512) maskw[i] = 0;
    loadW(0, Wb0);
    float4 svA[2], svB[2];
    loadS(svA, 0);
    loadS(svB, 1);
    asm volatile("s_waitcnt lgkmcnt(0)" ::: "memory");
    __builtin_amdgcn_sched_barrier(0);
    __builtin_amdgcn_s_barrier();
    __builtin_amdgcn_sched_barrier(0);

    #define BODY(SV, C, SB, WBC, WBN) do {                                   \
        stageS(SV, SB, (C));                                                 \
        loadS(SV, ((C) + 2 > 37) ? 37 : (C) + 2);                            \
        asm volatile("s_waitcnt lgkmcnt(0)" ::: "memory");                   \
        __builtin_amdgcn_sched_barrier(0);                                   \
        __builtin_amdgcn_s_barrier();                                        \
        __builtin_amdgcn_sched_barrier(0);                                   \
        loadW((C) + 1, WBN);                                                 \
        __builtin_amdgcn_sched_barrier(0);                                   \
        asm volatile("s_waitcnt vmcnt(5)" ::: "memory");                     \
        mfmaC(WBC, SB);                                                      \
    } while (0)

    #pragma unroll 1
    for (int p = 0; p < 18; ++p) {
        BODY(svA, 2 * p,     Sb0, Wb0, Wb1);
        BODY(svB, 2 * p + 1, Sb1, Wb1, Wb0);
    }
    BODY(svA, 36, Sb0, Wb0, Wb1);
    // peeled chunk 37
    stageS(svB, Sb1, 37);
    asm volatile("s_waitcnt lgkmcnt(0)" ::: "memory");
    __builtin_amdgcn_sched_barrier(0);
    __builtin_amdgcn_s_barrier();
    __builtin_amdgcn_sched_barrier(0);
    asm volatile("s_waitcnt vmcnt(0)" ::: "memory");
    mfmaC(Wb1, Sb1);
    #undef BODY

    // epilogue -> X1g [16384][384], cols n0..n0+191
    {
        const int nq4 = (lane >> 4) * 4;
        #pragma unroll
        for (int f = 0; f < 3; ++f) {
            int n4 = n0 + wn0 + f * 16 + nq4;
            float bv0 = b1[n4 / 3], bv1 = b1[(n4 + 1) / 3];
            float bv2 = b1[(n4 + 2) / 3], bv3 = b1[(n4 + 3) / 3];
            #pragma unroll
            for (int mi = 0; mi < 2; ++mi) {
                int m = mbase + mi * 16 + ml;
                ushort4 o;
                o.x = f2bf(fmaxf(acc[f][mi][0] + bv0, 0.f));
                o.y = f2bf(fmaxf(acc[f][mi][1] + bv1, 0.f));
                o.z = f2bf(fmaxf(acc[f][mi][2] + bv2, 0.f));
                o.w = f2bf(fmaxf(acc[f][mi][3] + bv3, 0.f));
                *(ushort4*)(X1g + (size_t)(m0 + m) * 384 + n4) = o;
            }
        }
    }

    // finalize combined mask (only the y==0 copy writes; both computed identically)
    if (blockIdx.y == 0 && tid < 64) {
        uint32_t* mw = &maskw[tid * 25];
        const u64 M40 = (1ull << 40) - 1;
        u64 ua = 0; uint32_t cf = 0;
        #pragma unroll
        for (int g = 0; g < 5; ++g) {
            uint32_t w0 = mw[5*g], w1 = mw[5*g+1], w2 = mw[5*g+2], w3 = mw[5*g+3], w4 = mw[5*g+4];
            u64 c0 = ( (u64)w0        | ((u64)w1 << 32)) & M40;
            u64 c1 = (((u64)w1 >> 8)  | ((u64)w2 << 24)) & M40;
            u64 c2 = (((u64)w2 >> 16) | ((u64)w3 << 16)) & M40;
            u64 c3 = (((u64)w3 >> 24) | ((u64)w4 << 8))  & M40;
            ua |= c0 | c1 | c2 | c3;
            if (__popcll(c0) >= 2) cf |= 1u << (4*g);
            if (__popcll(c1) >= 2) cf |= 1u << (4*g+1);
            if (__popcll(c2) >= 2) cf |= 1u << (4*g+2);
            if (__popcll(c3) >= 2) cf |= 1u << (4*g+3);
        }
        uint32_t* mg = maskg + (size_t)(m0 + tid) * 25;
        #pragma unroll
        for (int g = 0; g < 5; ++g) {
            uint32_t w0 = mw[5*g], w1 = mw[5*g+1], w2 = mw[5*g+2], w3 = mw[5*g+3], w4 = mw[5*g+4];
            u64 c0 = ( (u64)w0        | ((u64)w1 << 32)) & M40;
            u64 c1 = (((u64)w1 >> 8)  | ((u64)w2 << 24)) & M40;
            u64 c2 = (((u64)w2 >> 16) | ((u64)w3 << 16)) & M40;
            u64 c3 = (((u64)w3 >> 24) | ((u64)w4 << 8))  & M40;
            u64 m0v = c0 | ua | (((cf >> (4*g))     & 1u) ? M40 : 0ull);
            u64 m1v = c1 | ua | (((cf >> (4*g + 1)) & 1u) ? M40 : 0ull);
            u64 m2v = c2 | ua | (((cf >> (4*g + 2)) & 1u) ? M40 : 0ull);
            u64 m3v = c3 | ua | (((cf >> (4*g + 3)) & 1u) ? M40 : 0ull);
            mg[5*g]   = (uint32_t)m0v;
            mg[5*g+1] = (uint32_t)(m0v >> 32) | (uint32_t)(m1v << 8);
            mg[5*g+2] = (uint32_t)(m1v >> 24) | (uint32_t)(m2v << 16);
            mg[5*g+3] = (uint32_t)(m2v >> 16) | (uint32_t)(m3v << 24);
            mg[5*g+4] = (uint32_t)(m3v >> 8);
        }
    }
}

// ---------------- per-layer pipelined GEMM (layers 2..4, unchanged) ----------------
template<int MT, int NT, int K, int MF, int NF, int NWM, bool BDIV3>
__global__ __launch_bounds__(512)
void glayer(const ushort* __restrict__ Xg, const ushort* __restrict__ WT,
            const float* __restrict__ bias, ushort* __restrict__ Yg, int Nout)
{
    constexpr int NC   = K / 64;
    constexpr int AOCT = K / 8;
    constexpr int APT  = MT * AOCT / 512;
    constexpr int WPT  = NT * 8 / 512;
    extern __shared__ char lds[];
    char* Albuf = lds;
    char* Wbuf0 = lds + MT * K * 2;
    char* Wbuf1 = Wbuf0 + NT * 128;

    const int tid = threadIdx.x, lane = tid & 63, wid = tid >> 6;
    const int m0 = blockIdx.x * MT;
    const int n0 = blockIdx.y * NT;
    const int ml = lane & 15, kq = lane >> 4;
    const int mbase = (NWM == 1) ? 0 : (wid >> 2) * (MT / 2);
    const int wn0 = ((NWM == 1) ? wid : (wid & 3)) * (NF * 16);

    f32x4 acc[NF][MF];
    #pragma unroll
    for (int f = 0; f < NF; ++f)
        #pragma unroll
        for (int mi = 0; mi < MF; ++mi) acc[f][mi] = (f32x4){0.f, 0.f, 0.f, 0.f};

    auto loadW = [&](int c, char* dst) {
        #pragma unroll
        for (int i = 0; i < WPT; ++i) {
            int s = i * 512 + tid;
            int r = s >> 3, o = s & 7;
            gload_lds16(WT + (size_t)(n0 + r) * K + c * 64 + ((o ^ (r & 7)) * 8),
                        dst + s * 16);
        }
    };
    auto mfmaC = [&](const char* wb, int c) {
        #pragma unroll
        for (int ks = 0; ks < 2; ++ks) {
            bf16x8 af[NF], bv[MF];
            #pragma unroll
            for (int f = 0; f < NF; ++f) {
                int n = wn0 + f * 16 + ml;
                af[f] = *(const bf16x8*)(wb + n * 128 + (((ks * 4 + kq) * 16) ^ ((n & 7) << 4)));
            }
            #pragma unroll
            for (int mi = 0; mi < MF; ++mi) {
                int m = mbase + mi * 16 + ml;
                bv[mi] = *(const bf16x8*)(Albuf + m * (2 * K) +
                            ((((c * 2 + ks) * 4 + kq) * 16) ^ ((m & 7) << 4)));
            }
            #pragma unroll
            for (int f = 0; f < NF; ++f)
                #pragma unroll
                for (int mi = 0; mi < MF; ++mi)
                    acc[f][mi] = __builtin_amdgcn_mfma_f32_16x16x32_bf16(af[f], bv[mi], acc[f][mi], 0, 0, 0);
        }
    };

    #pragma unroll
    for (int i = 0; i < APT; ++i) {
        int s = i * 512 + tid;
        int r = s / AOCT, o = s - r * AOCT;
        int go = (o & ~7) | ((o & 7) ^ (r & 7));
        gload_lds16(Xg + (size_t)(m0 + r) * K + go * 8, Albuf + s * 16);
    }
    loadW(0, Wbuf0);
    VMCNT0_BAR();

    #pragma unroll 1
    for (int c = 0; c < NC; ++c) {
        if (c + 1 < NC) loadW(c + 1, (c & 1) ? Wbuf0 : Wbuf1);
        mfmaC((c & 1) ? Wbuf1 : Wbuf0, c);
        if (c + 1 < NC) VMCNT0_BAR();
    }

    const int nq4 = (lane >> 4) * 4;
    #pragma unroll
    for (int f = 0; f < NF; ++f) {
        int n4 = n0 + wn0 + f * 16 + nq4;
        float bv0 = bias[BDIV3 ? n4 / 3 : n4];
        float bv1 = bias[BDIV3 ? (n4 + 1) / 3 : n4 + 1];
        float bv2 = bias[BDIV3 ? (n4 + 2) / 3 : n4 + 2];
        float bv3 = bias[BDIV3 ? (n4 + 3) / 3 : n4 + 3];
        #pragma unroll
        for (int mi = 0; mi < MF; ++mi) {
            int m = mbase + mi * 16 + ml;
            ushort4 o;
            o.x = f2bf(fmaxf(acc[f][mi][0] + bv0, 0.f));
            o.y = f2bf(fmaxf(acc[f][mi][1] + bv1, 0.f));
            o.z = f2bf(fmaxf(acc[f][mi][2] + bv2, 0.f));
            o.w = f2bf(fmaxf(acc[f][mi][3] + bv3, 0.f));
            *(ushort4*)(Yg + (size_t)(m0 + m) * Nout + n4) = o;
        }
    }
}

// ---------------- lin2 (unchanged) ----------------
__global__ __launch_bounds__(512)
void lin2_kernel(const ushort* __restrict__ Xg, const ushort* __restrict__ WT,
                 const float* __restrict__ bias, const uint32_t* __restrict__ maskg,
                 float* __restrict__ out)
{
    constexpr int MT = 64, NT = 448, K = 192, NC = 3, MF = 2, NF = 7;
    constexpr int AOCT = K / 8;
    extern __shared__ char lds[];
    char* Albuf = lds;
    char* Wbuf0 = lds + MT * K * 2;
    char* Wbuf1 = Wbuf0 + NT * 128;

    const int tid = threadIdx.x, lane = tid & 63, wid = tid >> 6;
    const int m0 = blockIdx.x * MT;
    const int n0 = blockIdx.y * NT;
    const int ml = lane & 15, kq = lane >> 4;
    const int mbase = (wid >> 2) * 32;
    const int wn0 = (wid & 3) * 112;

    f32x4 acc[NF][MF];
    #pragma unroll
    for (int f = 0; f < NF; ++f)
        #pragma unroll
        for (int mi = 0; mi < MF; ++mi) acc[f][mi] = (f32x4){0.f, 0.f, 0.f, 0.f};

    auto loadW = [&](int c, char* dst) {
        #pragma unroll
        for (int i = 0; i < 7; ++i) {
            int s = i * 512 + tid;
            int r = s >> 3, o = s & 7;
            gload_lds16(WT + (size_t)(n0 + r) * K + c * 64 + ((o ^ (r & 7)) * 8),
                        dst + s * 16);
        }
    };
    auto mfmaC = [&](const char* wb, int c) {
        #pragma unroll
        for (int ks = 0; ks < 2; ++ks) {
            bf16x8 af[NF], bv[MF];
            #pragma unroll
            for (int f = 0; f < NF; ++f) {
                int n = wn0 + f * 16 + ml;
                af[f] = *(const bf16x8*)(wb + n * 128 + (((ks * 4 + kq) * 16) ^ ((n & 7) << 4)));
            }
            #pragma unroll
            for (int mi = 0; mi < MF; ++mi) {
                int m = mbase + mi * 16 + ml;
                bv[mi] = *(const bf16x8*)(Albuf + m * (2 * K) +
                            ((((c * 2 + ks) * 4 + kq) * 16) ^ ((m & 7) << 4)));
            }
            #pragma unroll
            for (int f = 0; f < NF; ++f)
                #pragma unroll
                for (int mi = 0; mi < MF; ++mi)
                    acc[f][mi] = __builtin_amdgcn_mfma_f32_16x16x32_bf16(af[f], bv[mi], acc[f][mi], 0, 0, 0);
        }
    };

    #pragma unroll
    for (int i = 0; i < 3; ++i) {
        int s = i * 512 + tid;
        int r = s / AOCT, o = s - r * AOCT;
        int go = (o & ~7) | ((o & 7) ^ (r & 7));
        gload_lds16(Xg + (size_t)(m0 + r) * K + go * 8, Albuf + s * 16);
    }
    loadW(0, Wbuf0);
    VMCNT0_BAR();

    #pragma unroll 1
    for (int c = 0; c < NC; ++c) {
        if (c + 1 < NC) loadW(c + 1, (c & 1) ? Wbuf0 : Wbuf1);
        mfmaC((c & 1) ? Wbuf1 : Wbuf0, c);
        if (c + 1 < NC) VMCNT0_BAR();
    }

    const int nq4 = (lane >> 4) * 4;
    #pragma unroll
    for (int f = 0; f < NF; ++f) {
        int nf = n0 + wn0 + f * 16;
        if (nf < 800) {
            int n4 = nf + nq4, sh = n4 & 31;
            float bv0 = bias[n4], bv1 = bias[n4 + 1], bv2 = bias[n4 + 2], bv3 = bias[n4 + 3];
            #pragma unroll
            for (int mi = 0; mi < MF; ++mi) {
                int m = mbase + mi * 16 + ml;
                uint32_t mwv = maskg[(size_t)(m0 + m) * 25 + (nf >> 5)];
                float4 v;
                v.x = ((mwv >> (sh + 0)) & 1u) ? NEG_HUGE : (acc[f][mi][0] + bv0);
                v.y = ((mwv >> (sh + 1)) & 1u) ? NEG_HUGE : (acc[f][mi][1] + bv1);
                v.z = ((mwv >> (sh + 2)) & 1u) ? NEG_HUGE : (acc[f][mi][2] + bv2);
                v.w = ((mwv >> (sh + 3)) & 1u) ? NEG_HUGE : (acc[f][mi][3] + bv3);
                *(float4*)(out + (size_t)(m0 + m) * 800 + n4) = v;
            }
        }
    }
}

__global__ void ws_fail_kernel(float* out) {
    if (threadIdx.x == 0 && blockIdx.x == 0) out[0] = NAN;
}

extern "C" void kernel_launch(void* const* d_in, const int* in_sizes, int n_in,
                              void* d_out, int out_size, void* d_ws, size_t ws_size,
                              hipStream_t stream) {
    const float* state = (const float*)d_in[0];
    const float* w1  = (const float*)d_in[1];
    const float* b1  = (const float*)d_in[2];
    const float* w2  = (const float*)d_in[3];
    const float* b2  = (const float*)d_in[4];
    const float* w3  = (const float*)d_in[5];
    const float* b3  = (const float*)d_in[6];
    const float* wl1 = (const float*)d_in[7];
    const float* bl1 = (const float*)d_in[8];
    const float* wl2 = (const float*)d_in[9];
    const float* bl2 = (const float*)d_in[10];
    float* out = (float*)d_out;

    char* ws = (char*)d_ws;
    size_t off = 0;
    auto carve = [&](size_t bytes) {
        char* p = ws + off;
        off = (off + bytes + 255) & ~(size_t)255;
        return p;
    };
    ushort* W1T  = (ushort*)carve(384ull * 2432 * 2);
    ushort* W2T  = (ushort*)carve(768ull * 384 * 2);
    ushort* W3T  = (ushort*)carve(384ull * 768 * 2);
    ushort* WL1T = (ushort*)carve(192ull * 384 * 2);
    ushort* WL2T = (ushort*)carve(896ull * 192 * 2);
    ushort* X1g  = (ushort*)carve(16384ull * 384 * 2);
    ushort* X2g  = (ushort*)carve(16384ull * 768 * 2);
    ushort* X3g  = (ushort*)carve(16384ull * 384 * 2);
    ushort* X4g  = (ushort*)carve(16384ull * 192 * 2);
    uint32_t* maskg = (uint32_t*)carve(16384ull * 25 * 4);

    if (off > ws_size) {
        ws_fail_kernel<<<1, 64, 0, stream>>>(out);
        return;
    }

    prep_conv_T<<<(384 * 2432 + 255) / 256, 256, 0, stream>>>(w1, W1T, 800, 128, 384, 2432);
    prep_conv_T<<<(768 * 384 + 255) / 256, 256, 0, stream>>>(w2, W2T, 128, 256, 768, 384);
    prep_conv_T<<<(384 * 768 + 255) / 256, 256, 0, stream>>>(w3, W3T, 256, 128, 384, 768);
    prep_lin_T<<<(192 * 384 + 255) / 256, 256, 0, stream>>>(wl1, WL1T, 384, 192, 192);
    prep_lin_T<<<(896 * 192 + 255) / 256, 256, 0, stream>>>(wl2, WL2T, 192, 800, 896);

    hipFuncSetAttribute(reinterpret_cast<const void*>(conv1_kernel),
                        hipFuncAttributeMaxDynamicSharedMemorySize, 71936);
    conv1_kernel<<<dim3(256, 2), 512, 71936, stream>>>(state, W1T, b1, X1g, maskg);

    auto k2 = glayer<64, 384, 384, 4, 3, 1, true>;
    hipFuncSetAttribute(reinterpret_cast<const void*>(k2),
                        hipFuncAttributeMaxDynamicSharedMemorySize, 147456);
    k2<<<dim3(256, 2), 512, 147456, stream>>>(X1g, W2T, b2, X2g, 768);

    auto k3 = glayer<32, 384, 768, 2, 3, 1, true>;
    hipFuncSetAttribute(reinterpret_cast<const void*>(k3),
                        hipFuncAttributeMaxDynamicSharedMemorySize, 147456);
    k3<<<dim3(512, 1), 512, 147456, stream>>>(X2g, W3T, b3, X3g, 384);

    auto k4 = glayer<32, 192, 384, 1, 3, 2, false>;
    hipFuncSetAttribute(reinterpret_cast<const void*>(k4),
                        hipFuncAttributeMaxDynamicSharedMemorySize, 73728);
    k4<<<dim3(512, 1), 512, 73728, stream>>>(X3g, WL1T, bl1, X4g, 192);

    hipFuncSetAttribute(reinterpret_cast<const void*>(lin2_kernel),
                        hipFuncAttributeMaxDynamicSharedMemorySize, 139264);
    lin2_kernel<<<dim3(256, 2), 512, 139264, stream>>>(X4g, WL2T, bl2, maskg, out);
}